// Round 4
// baseline (288.645 us; speedup 1.0000x reference)
//
#include <hip/hip_runtime.h>
#include <hip/hip_bf16.h>

typedef __attribute__((ext_vector_type(8))) short short8v;
typedef __attribute__((ext_vector_type(4))) float floatx4;

#define KTOT 262144L                     // 64^3
#define WT_BYTES (128L * KTOT * 2L)      // 67,108,864 B: Wt[n][k] bf16 in d_ws

__device__ __forceinline__ unsigned int pkbf(float a, float b) {
  __hip_bfloat162 h = __float22bfloat162_rn(make_float2(a, b));
  union { __hip_bfloat162 h; unsigned int u; } c; c.h = h;
  return c.u;
}

// ---------------- W [262144][128] fp32 -> Wt [128][262144] bf16 ----------------
__global__ __launch_bounds__(512)
void transpose_w(const float* __restrict__ W, short* __restrict__ Wt) {
  __shared__ float T[128][129];
  const long k0 = (long)blockIdx.x << 7;   // 128 k-rows per block, 2048 blocks
  const int tid = threadIdx.x;

  {   // coalesced read: lanes along n
    const int n = tid & 127, ks = tid >> 7;          // ks 0..3
    #pragma unroll 8
    for (int r = 0; r < 32; ++r) {
      int k = (ks << 5) + r;
      T[k][n] = W[(k0 + k) * 128 + n];
    }
  }
  __syncthreads();
  {   // write k-contiguous bf16: thread owns (n, 32-k chunk)
    const int n = tid >> 2, kq = tid & 3;
    #pragma unroll
    for (int u = 0; u < 4; ++u) {
      int kb = (kq << 5) + (u << 3);                 // k base, multiple of 8
      union { short8v v; unsigned int w[4]; } pk;
      #pragma unroll
      for (int v2 = 0; v2 < 4; ++v2)
        pk.w[v2] = pkbf(T[kb + 2 * v2][n], T[kb + 2 * v2 + 1][n]);
      *(short8v*)(Wt + (long)n * KTOT + k0 + kb) = pk.v;
    }
  }
}

// ---------------- reduce 256 K-partials + bias -> out ----------------
__global__ __launch_bounds__(128)
void reduce_k(const float* __restrict__ part, const float* __restrict__ bias,
              float* __restrict__ out) {
  int o = blockIdx.x * 128 + threadIdx.x;     // 0..32767
  const float* p = part + o;
  float s0 = 0.f, s1 = 0.f, s2 = 0.f, s3 = 0.f;
  #pragma unroll 8
  for (int c = 0; c < 256; c += 4) {
    s0 += p[(long)c * 32768];
    s1 += p[(long)(c + 1) * 32768];
    s2 += p[(long)(c + 2) * 32768];
    s3 += p[(long)(c + 3) * 32768];
  }
  out[o] = s0 + s1 + s2 + s3 + bias[o & 127];
}

// ---------------- main GEMM, B-operand from pre-transposed bf16 Wt ----------------
// partial_c[256,128] = F[256, Kchunk_c] @ W[Kchunk_c, 128]
// F[b,gk] = a[b,i]*p[b,j]*d[b,k], gk=(i*64+j)*64+k; block c: i=c>>2, j in [(c&3)*16,+16), k in [0,64)
__global__ __launch_bounds__(512, 2)
void tfn_gemm_bt(const float* __restrict__ X, const float* __restrict__ P,
                 const float* __restrict__ Dyn, const short* __restrict__ Wt,
                 float* __restrict__ part) {
  __shared__ float p_lds[16][256];            // p[jj][brow]

  const int tid = threadIdx.x;
  const int wv = tid >> 6, lane = tid & 63;
  const int q = lane >> 4, l16 = lane & 15;
  const int r = wv & 3;                       // rows [64r, 64r+64)
  const int cg = wv >> 2;                     // cols [64cg, 64cg+64)

  const int c = blockIdx.x;
  const int i = c >> 2;
  const int j0 = (c & 3) << 4;
  const long gk0 = (long)c << 10;

  for (int idx = tid; idx < 256 * 16; idx += 512) {
    int bb = idx >> 4, jj = idx & 15;
    int j = j0 + jj;
    p_lds[jj][bb] = (j < 63) ? P[bb * 63 + j] : 1.0f;
  }

  // e[rt][h][t] = a * d  (all indices compile-time in the loop)
  float e[4][2][8];
  #pragma unroll
  for (int rt = 0; rt < 4; ++rt) {
    int brow = (r << 6) + (rt << 4) + l16;
    float av = (i < 63) ? X[brow * 63 + i] : 1.0f;
    #pragma unroll
    for (int h = 0; h < 2; ++h) {
      int kb = (h << 5) + (q << 3);
      #pragma unroll
      for (int t = 0; t < 8; ++t) {
        int k = kb + t;
        float dv = (k < 63) ? Dyn[brow * 63 + k] : 1.0f;
        e[rt][h][t] = av * dv;
      }
    }
  }

  floatx4 acc[4][4];
  #pragma unroll
  for (int a = 0; a < 4; ++a)
    #pragma unroll
    for (int b = 0; b < 4; ++b) acc[a][b] = (floatx4)0.0f;

  __syncthreads();   // only barrier in the kernel

  // B-fragment source: lane (q,l16), tile nt, step s reads 8 k-contiguous bf16 at
  // Wt[(cg*64+nt*16+l16)*K + gk0 + s*32 + q*8]  -- 16B aligned
  const short* wrow = Wt + ((long)((cg << 6) + l16)) * KTOT + gk0 + (q << 3);
  const short* wp[4];
  #pragma unroll
  for (int nt = 0; nt < 4; ++nt) wp[nt] = wrow + (long)nt * (KTOT << 4);

#define COMPUTE(jj, buf)                                                          \
  {                                                                               \
    float pb[4];                                                                  \
    _Pragma("unroll") for (int rt = 0; rt < 4; ++rt)                              \
        pb[rt] = p_lds[jj][(r << 6) + (rt << 4) + l16];                           \
    _Pragma("unroll") for (int h = 0; h < 2; ++h) {                               \
      union { short8v v; unsigned int u[4]; } fa[4];                              \
      _Pragma("unroll") for (int rt = 0; rt < 4; ++rt)                            \
          _Pragma("unroll") for (int v2 = 0; v2 < 4; ++v2)                        \
              fa[rt].u[v2] = pkbf(pb[rt] * e[rt][h][2 * v2],                      \
                                  pb[rt] * e[rt][h][2 * v2 + 1]);                 \
      _Pragma("unroll") for (int rt = 0; rt < 4; ++rt)                            \
          _Pragma("unroll") for (int nt = 0; nt < 4; ++nt)                        \
              acc[rt][nt] = __builtin_amdgcn_mfma_f32_16x16x32_bf16(              \
                  fa[rt].v, (buf)[h][nt], acc[rt][nt], 0, 0, 0);                  \
    }                                                                             \
  }

  short8v bufA[2][4], bufB[2][4];
  #pragma unroll
  for (int h = 0; h < 2; ++h)
    #pragma unroll
    for (int nt = 0; nt < 4; ++nt)
      bufA[h][nt] = *(const short8v*)(wp[nt] + h * 32);          // jj = 0

  for (int jj2 = 0; jj2 < 8; ++jj2) {
    const int jjA = jj2 << 1, jjB = jjA + 1;
    // phase A: prefetch jjB, compute jjA
    #pragma unroll
    for (int h = 0; h < 2; ++h)
      #pragma unroll
      for (int nt = 0; nt < 4; ++nt)
        bufB[h][nt] = *(const short8v*)(wp[nt] + ((jjB << 1) + h) * 32);
    COMPUTE(jjA, bufA);
    // phase B: prefetch jjB+1 (jj2=7 over-reads <=112B into d_ws partials region,
    // values never used), compute jjB
    #pragma unroll
    for (int h = 0; h < 2; ++h)
      #pragma unroll
      for (int nt = 0; nt < 4; ++nt)
        bufA[h][nt] = *(const short8v*)(wp[nt] + (((jjB + 1) << 1) + h) * 32);
    COMPUTE(jjB, bufB);
  }
#undef COMPUTE

  float* pt = part + ((long)c << 15);
  #pragma unroll
  for (int rt = 0; rt < 4; ++rt)
    #pragma unroll
    for (int nt = 0; nt < 4; ++nt) {
      int col = (cg << 6) + (nt << 4) + l16;
      #pragma unroll
      for (int g = 0; g < 4; ++g) {
        int brow = (r << 6) + (rt << 4) + (q << 2) + g;
        pt[brow * 128 + col] = acc[rt][nt][g];
      }
    }
}

// ---------------- fallback (no workspace): R3 atomic version ----------------
__global__ void bias_init(const float* __restrict__ bias, float* __restrict__ out) {
  int idx = blockIdx.x * 256 + threadIdx.x;
  out[idx] = bias[idx & 127];
}

__global__ __launch_bounds__(512, 2)
void tfn_gemm_fb(const float* __restrict__ X, const float* __restrict__ P,
                 const float* __restrict__ Dyn, const float* __restrict__ W,
                 float* __restrict__ out) {
  __shared__ float p_lds[16][256];
  const int tid = threadIdx.x;
  const int wv = tid >> 6, lane = tid & 63;
  const int q = lane >> 4, l16 = lane & 15;
  const int r = wv & 3, cg = wv >> 2;
  const int c = blockIdx.x;
  const int i = c >> 2;
  const int j0 = (c & 3) << 4;
  const long gk0 = (long)c << 10;

  for (int idx = tid; idx < 256 * 16; idx += 512) {
    int bb = idx >> 4, jj = idx & 15;
    int j = j0 + jj;
    p_lds[jj][bb] = (j < 63) ? P[bb * 63 + j] : 1.0f;
  }
  float e[4][2][8];
  #pragma unroll
  for (int rt = 0; rt < 4; ++rt) {
    int brow = (r << 6) + (rt << 4) + l16;
    float av = (i < 63) ? X[brow * 63 + i] : 1.0f;
    #pragma unroll
    for (int h = 0; h < 2; ++h)
      #pragma unroll
      for (int t = 0; t < 8; ++t) {
        int k = (h << 5) + (q << 3) + t;
        e[rt][h][t] = av * ((k < 63) ? Dyn[brow * 63 + k] : 1.0f);
      }
  }
  floatx4 acc[4][4];
  #pragma unroll
  for (int a = 0; a < 4; ++a)
    #pragma unroll
    for (int b = 0; b < 4; ++b) acc[a][b] = (floatx4)0.0f;
  __syncthreads();

  const float* wstep = W + (gk0 + (q << 3)) * 128 + (cg << 6) + l16;
  for (int jj = 0; jj < 16; ++jj) {
    float pb[4];
    #pragma unroll
    for (int rt = 0; rt < 4; ++rt) pb[rt] = p_lds[jj][(r << 6) + (rt << 4) + l16];
    #pragma unroll
    for (int h = 0; h < 2; ++h) {
      const int s = (jj << 1) | h;
      union { short8v v; unsigned int u[4]; } fb[4], fa[4];
      #pragma unroll
      for (int nt = 0; nt < 4; ++nt) {
        const float* wpq = wstep + ((long)s << 12) + nt * 16;
        float wv8[8];
        #pragma unroll
        for (int t = 0; t < 8; ++t) wv8[t] = wpq[t * 128];
        #pragma unroll
        for (int v2 = 0; v2 < 4; ++v2) fb[nt].u[v2] = pkbf(wv8[2 * v2], wv8[2 * v2 + 1]);
      }
      #pragma unroll
      for (int rt = 0; rt < 4; ++rt)
        #pragma unroll
        for (int v2 = 0; v2 < 4; ++v2)
          fa[rt].u[v2] = pkbf(pb[rt] * e[rt][h][2 * v2], pb[rt] * e[rt][h][2 * v2 + 1]);
      #pragma unroll
      for (int rt = 0; rt < 4; ++rt)
        #pragma unroll
        for (int nt = 0; nt < 4; ++nt)
          acc[rt][nt] = __builtin_amdgcn_mfma_f32_16x16x32_bf16(
              fa[rt].v, fb[nt].v, acc[rt][nt], 0, 0, 0);
    }
  }
  #pragma unroll
  for (int rt = 0; rt < 4; ++rt)
    #pragma unroll
    for (int nt = 0; nt < 4; ++nt) {
      int col = (cg << 6) + (nt << 4) + l16;
      #pragma unroll
      for (int g = 0; g < 4; ++g) {
        int brow = (r << 6) + (rt << 4) + (q << 2) + g;
        atomicAdd(&out[brow * 128 + col], acc[rt][nt][g]);
      }
    }
}

extern "C" void kernel_launch(void* const* d_in, const int* in_sizes, int n_in,
                              void* d_out, int out_size, void* d_ws, size_t ws_size,
                              hipStream_t stream) {
  const float* x   = (const float*)d_in[0];
  const float* p   = (const float*)d_in[1];
  const float* dyn = (const float*)d_in[2];
  const float* W   = (const float*)d_in[3];
  const float* b   = (const float*)d_in[4];
  float* out = (float*)d_out;

  const size_t need = (size_t)WT_BYTES + (size_t)256 * 32768 * sizeof(float);
  if (d_ws != nullptr && ws_size >= need) {
    short* Wt   = (short*)d_ws;
    float* part = (float*)((char*)d_ws + WT_BYTES);
    transpose_w<<<2048, 512, 0, stream>>>(W, Wt);
    tfn_gemm_bt<<<256, 512, 0, stream>>>(x, p, dyn, Wt, part);
    reduce_k<<<256, 128, 0, stream>>>(part, b, out);
  } else {
    bias_init<<<128, 256, 0, stream>>>(b, out);
    tfn_gemm_fb<<<256, 512, 0, stream>>>(x, p, dyn, W, out);
  }
}

// Round 6
// 251.933 us; speedup vs baseline: 1.1457x; 1.1457x over previous
//
#include <hip/hip_runtime.h>
#include <hip/hip_bf16.h>

typedef __attribute__((ext_vector_type(8))) short short8v;
typedef __attribute__((ext_vector_type(4))) float floatx4;

__device__ __forceinline__ unsigned int pkbf(float a, float b) {
  __hip_bfloat162 h = __float22bfloat162_rn(make_float2(a, b));
  union { __hip_bfloat162 h; unsigned int u; } c; c.h = h;
  return c.u;
}

// out[b*128+o] = bias[o]
__global__ void bias_init(const float* __restrict__ bias, float* __restrict__ out) {
  int idx = blockIdx.x * 256 + threadIdx.x;   // 32768 total
  out[idx] = bias[idx & 127];
}

// ---------------- main GEMM: out[256,128] += F[256,Kc] @ W[Kc,128] ----------------
// F[b,gk] = a[b,i]*p[b,j]*d[b,k], gk=(i*64+j)*64+k
// block c: i=c>>2, j in [(c&3)*16,+16), k in [0,64). Barrier-free K-loop,
// direct fp32 W loads, prefetch distance = 2 half-steps (two in-flight reg sets).
// Epilogue: device-scope atomicAdd into out (bias pre-initialized). NO d_ws use.
__global__ __launch_bounds__(512, 2)
void tfn_gemm(const float* __restrict__ X, const float* __restrict__ P,
              const float* __restrict__ Dyn, const float* __restrict__ W,
              float* __restrict__ out) {
  __shared__ float p_lds[16][256];            // p[jj][brow]

  const int tid = threadIdx.x;
  const int wv = tid >> 6, lane = tid & 63;
  const int q = lane >> 4, l16 = lane & 15;
  const int r = wv & 3;                       // rows [64r, 64r+64)
  const int cg = wv >> 2;                     // cols [64cg, 64cg+64)

  const int c = blockIdx.x;
  const int i = c >> 2;
  const int j0 = (c & 3) << 4;
  const long gk0 = (long)c << 10;

  for (int idx = tid; idx < 256 * 16; idx += 512) {
    int bb = idx >> 4, jj = idx & 15;
    int j = j0 + jj;
    p_lds[jj][bb] = (j < 63) ? P[bb * 63 + j] : 1.0f;
  }

  // e[rt][h][t] = a * d  (indices compile-time everywhere in the loop)
  float e[4][2][8];
  #pragma unroll
  for (int rt = 0; rt < 4; ++rt) {
    int brow = (r << 6) + (rt << 4) + l16;
    float av = (i < 63) ? X[brow * 63 + i] : 1.0f;
    #pragma unroll
    for (int h = 0; h < 2; ++h) {
      int kb = (h << 5) + (q << 3);
      #pragma unroll
      for (int t = 0; t < 8; ++t) {
        int k = kb + t;
        float dv = (k < 63) ? Dyn[brow * 63 + k] : 1.0f;
        e[rt][h][t] = av * dv;
      }
    }
  }

  floatx4 acc[4][4];
  #pragma unroll
  for (int a = 0; a < 4; ++a)
    #pragma unroll
    for (int b = 0; b < 4; ++b) acc[a][b] = (floatx4)0.0f;

  __syncthreads();   // only barrier in the kernel

  // per-lane fragment base: element (s,t,nt) at wstep[s*4096 + t*128 + nt*16]
  const float* wstep = W + (gk0 + (q << 3)) * 128 + (cg << 6) + l16;
  const float* wp0 = wstep;            // even half-steps: s = 2jj
  const float* wp1 = wstep + 4096;     // odd half-steps:  s = 2jj+1

  float wf0[4][8], wf1[4][8];          // two fp32 in-flight sets [nt][t]

  #pragma unroll
  for (int nt = 0; nt < 4; ++nt)
    #pragma unroll
    for (int t = 0; t < 8; ++t) {
      wf0[nt][t] = wp0[t * 128 + nt * 16];   // s=0
      wf1[nt][t] = wp1[t * 128 + nt * 16];   // s=1
    }

#define FA_MFMA(h, fbv)                                                         \
  {                                                                             \
    union { short8v v; unsigned int u[4]; } fa[4];                              \
    _Pragma("unroll") for (int rt = 0; rt < 4; ++rt)                            \
        _Pragma("unroll") for (int v2 = 0; v2 < 4; ++v2)                        \
            fa[rt].u[v2] = pkbf(pb[rt] * e[rt][h][2 * v2],                      \
                                pb[rt] * e[rt][h][2 * v2 + 1]);                 \
    _Pragma("unroll") for (int rt = 0; rt < 4; ++rt)                            \
        _Pragma("unroll") for (int nt = 0; nt < 4; ++nt)                        \
            acc[rt][nt] = __builtin_amdgcn_mfma_f32_16x16x32_bf16(              \
                fa[rt].v, (fbv)[nt].v, acc[rt][nt], 0, 0, 0);                   \
  }

  for (int jj = 0; jj < 16; ++jj) {
    float pb[4];
    #pragma unroll
    for (int rt = 0; rt < 4; ++rt)
      pb[rt] = p_lds[jj][(r << 6) + (rt << 4) + l16];

    // ---- half-step s = 2jj: pack wf0 -> bf16, re-issue wf0 for s+2, compute ----
    union { short8v v; unsigned int u[4]; } fb0[4];
    #pragma unroll
    for (int nt = 0; nt < 4; ++nt)
      #pragma unroll
      for (int v2 = 0; v2 < 4; ++v2)
        fb0[nt].u[v2] = pkbf(wf0[nt][2 * v2], wf0[nt][2 * v2 + 1]);
    if (jj < 15) {
      const float* np = wp0 + 8192;          // s = 2jj+2
      #pragma unroll
      for (int nt = 0; nt < 4; ++nt)
        #pragma unroll
        for (int t = 0; t < 8; ++t)
          wf0[nt][t] = np[t * 128 + nt * 16];
    }
    FA_MFMA(0, fb0)

    // ---- half-step s = 2jj+1: pack wf1, re-issue wf1 for s+2, compute ----
    union { short8v v; unsigned int u[4]; } fb1[4];
    #pragma unroll
    for (int nt = 0; nt < 4; ++nt)
      #pragma unroll
      for (int v2 = 0; v2 < 4; ++v2)
        fb1[nt].u[v2] = pkbf(wf1[nt][2 * v2], wf1[nt][2 * v2 + 1]);
    if (jj < 15) {
      const float* np = wp1 + 8192;          // s = 2jj+3
      #pragma unroll
      for (int nt = 0; nt < 4; ++nt)
        #pragma unroll
        for (int t = 0; t < 8; ++t)
          wf1[nt][t] = np[t * 128 + nt * 16];
    }
    FA_MFMA(1, fb1)

    wp0 += 8192;
    wp1 += 8192;
  }
#undef FA_MFMA

  // epilogue: atomic accumulate, iteration order rotated by block to stagger
  // same-address contention (256 blocks hit disjoint ranges first)
  #pragma unroll
  for (int rt0 = 0; rt0 < 4; ++rt0) {
    #pragma unroll
    for (int nt0 = 0; nt0 < 4; ++nt0) {
      const int rt = (rt0 + (c >> 2)) & 3;
      const int nt = (nt0 + c) & 3;
      int col = (cg << 6) + (nt << 4) + l16;
      #pragma unroll
      for (int g = 0; g < 4; ++g) {
        int brow = (r << 6) + (rt << 4) + (q << 2) + g;
        atomicAdd(&out[brow * 128 + col], acc[rt][nt][g]);
      }
    }
  }
}

extern "C" void kernel_launch(void* const* d_in, const int* in_sizes, int n_in,
                              void* d_out, int out_size, void* d_ws, size_t ws_size,
                              hipStream_t stream) {
  const float* x   = (const float*)d_in[0];
  const float* p   = (const float*)d_in[1];
  const float* dyn = (const float*)d_in[2];
  const float* W   = (const float*)d_in[3];
  const float* b   = (const float*)d_in[4];
  float* out = (float*)d_out;

  bias_init<<<128, 256, 0, stream>>>(b, out);
  tfn_gemm<<<256, 512, 0, stream>>>(x, p, dyn, W, out);
}